// Round 18
// baseline (157.089 us; speedup 1.0000x reference)
//
#include <hip/hip_runtime.h>
#include <math.h>

#define T_TOK 4096
#define HDIM  1024
#define NEXP  16
#define IDIM  512
#define NSLOT 16384          // 8192 routed + 2*4096 shared-pseudo
#define NGRP  18
#define MAXRB 160            // 128-row blocks

typedef unsigned int u32;
typedef unsigned short u16;
typedef __attribute__((ext_vector_type(8))) short bfrag;   // 8 bf16 (4 VGPRs)
typedef __attribute__((ext_vector_type(4))) float f32x4;

__device__ __forceinline__ u16 f2bf(float f) {
    union { float f; u32 u; } c; c.f = f;
    u32 u = c.u;
    u32 r = u + 0x7fffu + ((u >> 16) & 1u);   // RNE
    return (u16)(r >> 16);
}
__device__ __forceinline__ float bf2f(u16 h) {
    union { u32 u; float f; } c; c.u = ((u32)h) << 16;
    return c.f;
}

__device__ __forceinline__ void async16(void* lds, const void* g) {
    __builtin_amdgcn_global_load_lds((__attribute__((address_space(1))) void*)(g),
                                     (__attribute__((address_space(3))) void*)(lds),
                                     16, 0, 0);
}

// counted-wait + raw barrier (never drain vmcnt to 0 inside the K-loop)
#define SYNCN(n) do { \
    asm volatile("s_waitcnt vmcnt(" #n ")" ::: "memory"); \
    __builtin_amdgcn_s_barrier(); \
    __builtin_amdgcn_sched_barrier(0); \
} while (0)
#define BAR2() do { \
    __builtin_amdgcn_s_barrier(); \
    __builtin_amdgcn_sched_barrier(0); \
} while (0)

// ---------------- fused prep: weight transposes via global_load_lds staging
// (16 outstanding loads/thread, zero VGPR cost) + router + x->bf16, ONE launch ----------------
// Blocks 0..1727: transpose 128x128 macro-tiles. Blocks 1728..2751: router (4 tokens each).
__device__ __forceinline__ void transpose_g2l(const float* __restrict__ src,
                                              u16* __restrict__ dst,
                                              int R, int C, long base, int bx, int by) {
    __shared__ float4 tile[128 * 32];     // 64 KB: row r = chunks r*32..r*32+31
    int c0 = bx * 128, r0 = by * 128;
    int t = threadIdx.x;
    // stage: linear LDS dest, source chunk XOR'd by (r>>2)&31 (involution per 4-row group)
#pragma unroll
    for (int c = 0; c < 16; ++c) {
        int idx = c * 256 + t;            // 0..4095
        int r = idx >> 5, ch = idx & 31;
        int sch = ch ^ ((r >> 2) & 31);
        async16(&tile[idx], src + base + (long)(r0 + r) * C + c0 + sch * 4);
    }
    asm volatile("s_waitcnt vmcnt(0)" ::: "memory");
    __syncthreads();
    // read back: thread handles 4x4 block (rows rq*4..+3, cols cg*4..+3)
#pragma unroll
    for (int q = 0; q < 4; ++q) {
        int oidx = q * 256 + t;           // 0..1023
        int cg = oidx >> 5, rq = oidx & 31;
        int p = cg ^ rq;                  // matches staging key for rows rq*4..rq*4+3
        float4 L[4];
#pragma unroll
        for (int j = 0; j < 4; ++j)
            L[j] = tile[(rq * 4 + j) * 32 + p];
#pragma unroll
        for (int i = 0; i < 4; ++i) {
            int c = cg * 4 + i;
            ushort4 o;
            o.x = f2bf(((const float*)&L[0])[i]);
            o.y = f2bf(((const float*)&L[1])[i]);
            o.z = f2bf(((const float*)&L[2])[i]);
            o.w = f2bf(((const float*)&L[3])[i]);
            *(ushort4*)(dst + base + (long)(c0 + c) * R + r0 + rq * 4) = o;
        }
    }
}

__global__ __launch_bounds__(256)
void prep_k(const float* __restrict__ x, const float* __restrict__ rw,
            const float* __restrict__ bias,
            const float* __restrict__ wg, const float* __restrict__ wu,
            const float* __restrict__ wd, const float* __restrict__ swg,
            const float* __restrict__ swu, const float* __restrict__ swd,
            u16* __restrict__ WtG, u16* __restrict__ WtU, u16* __restrict__ WtD,
            u16* __restrict__ SWtG, u16* __restrict__ SWtU, u16* __restrict__ SWtD,
            int* __restrict__ sel, float* __restrict__ wts, u16* __restrict__ x_bf) {
    int b = blockIdx.x;
    if (b < 512) {                        // wg: 16 x [1024][512] -> [512][1024]; 32 tiles/e (4C x 8R)
        int e = b >> 5, t = b & 31;
        transpose_g2l(wg, WtG, HDIM, IDIM, (long)e * HDIM * IDIM, t & 3, t >> 2);
        return;
    } else if (b < 1024) {                // wu
        int bb = b - 512, e = bb >> 5, t = bb & 31;
        transpose_g2l(wu, WtU, HDIM, IDIM, (long)e * HDIM * IDIM, t & 3, t >> 2);
        return;
    } else if (b < 1536) {                // wd: 16 x [512][1024] -> [1024][512]; 32 tiles/e (8C x 4R)
        int bb = b - 1024, e = bb >> 5, t = bb & 31;
        transpose_g2l(wd, WtD, IDIM, HDIM, (long)e * IDIM * HDIM, t & 7, t >> 3);
        return;
    } else if (b < 1600) {                // swg: [1024][1024]; 64 tiles (8C x 8R)
        int t = b - 1536;
        transpose_g2l(swg, SWtG, HDIM, 2 * IDIM, 0, t & 7, t >> 3);
        return;
    } else if (b < 1664) {                // swu
        int t = b - 1600;
        transpose_g2l(swu, SWtU, HDIM, 2 * IDIM, 0, t & 7, t >> 3);
        return;
    } else if (b < 1728) {                // swd as 2 pseudo [512][1024] -> [1024][512]; 32 tiles each
        int t = b - 1664, z = t >> 5, tt = t & 31;
        transpose_g2l(swd, SWtD, IDIM, HDIM, (long)z * IDIM * HDIM, tt & 7, tt >> 3);
        return;
    }
    // ---- router part: blocks 1728..2751, one wave per token ----
    int tid = threadIdx.x;
    int wv = tid >> 6;
    int lane = tid & 63;
    int t = (b - 1728) * 4 + wv;

    // emit bf16 row (coalesced: 64 lanes x 16B)
    const float4* xr4 = (const float4*)(x + (long)t * HDIM);
    ushort4* xb4 = (ushort4*)(x_bf + (long)t * HDIM);
#pragma unroll
    for (int j = 0; j < 4; ++j) {
        float4 v = xr4[lane + j * 64];
        ushort4 ov;
        ov.x = f2bf(v.x); ov.y = f2bf(v.y); ov.z = f2bf(v.z); ov.w = f2bf(v.w);
        xb4[lane + j * 64] = ov;
    }

    int e = lane & 15, hc = lane >> 4;
    const float* xr = x + (long)t * HDIM + hc * 256;
    const float* rp = rw + (long)hc * 256 * NEXP + e;
    float acc = 0.f;
#pragma unroll 4
    for (int i = 0; i < 64; ++i) {
        float4 xv = *(const float4*)(xr + i * 4);
        acc += xv.x * rp[(i * 4 + 0) * NEXP] + xv.y * rp[(i * 4 + 1) * NEXP]
             + xv.z * rp[(i * 4 + 2) * NEXP] + xv.w * rp[(i * 4 + 3) * NEXP];
    }
    acc += __shfl_down(acc, 16);
    acc += __shfl_down(acc, 32);
    float sc = 1.f / (1.f + __expf(-acc));     // valid on lanes 0..15
    float v = sc + bias[e];
    int i0 = -1, i1 = -1;
    float v0 = -1e30f, v1 = -1e30f, s0 = 0.f, s1 = 0.f;
#pragma unroll
    for (int j = 0; j < 16; ++j) {
        float vj = __shfl(v, j);
        float scj = __shfl(sc, j);
        if (vj > v0) { v1 = v0; i1 = i0; s1 = s0; v0 = vj; i0 = j; s0 = scj; }
        else if (vj > v1) { v1 = vj; i1 = j; s1 = scj; }
    }
    if (lane == 0) {
        float nrm = s0 + s1 + 1e-20f;
        sel[t * 2] = i0; sel[t * 2 + 1] = i1;
        wts[t * 2] = s0 / nrm; wts[t * 2 + 1] = s1 / nrm;
    }
}

// ---------------- routing build: single block, LDS atomics only ----------------
__global__ __launch_bounds__(1024) void route_build_k(const int* __restrict__ sel,
                                                      int* __restrict__ offs,
                                                      int* __restrict__ rowmap,
                                                      int* __restrict__ invmap,
                                                      int* __restrict__ rbGroup,
                                                      int* __restrict__ rbRow0) {
    __shared__ int hist[NEXP];
    __shared__ int cur[NEXP];
    int tid = threadIdx.x;
    if (tid < NEXP) hist[tid] = 0;
    __syncthreads();
    for (int i = tid; i < T_TOK * 2; i += 1024)
        atomicAdd(&hist[sel[i]], 1);
    __syncthreads();
    if (tid == 0) {
        int a = 0;
        for (int g = 0; g < NEXP; ++g) { cur[g] = a; offs[g] = a; a += hist[g]; }
        offs[16] = 8192;
        offs[17] = 8192 + T_TOK;
        offs[18] = 8192 + 2 * T_TOK;
        int rb = 0;
        for (int g = 0; g < NGRP; ++g)
            for (int r0 = offs[g]; r0 < offs[g + 1]; r0 += 128) {
                rbGroup[rb] = g; rbRow0[rb] = r0; ++rb;
            }
        for (; rb < MAXRB; ++rb) rbGroup[rb] = -1;
    }
    __syncthreads();
    for (int i = tid; i < T_TOK * 2; i += 1024) {
        int g = sel[i];
        int slot = atomicAdd(&cur[g], 1);
        rowmap[slot] = i >> 1;
        invmap[i] = slot;
    }
    for (int i = tid; i < T_TOK; i += 1024) {
        rowmap[8192 + i] = i;
        rowmap[8192 + T_TOK + i] = i;
    }
}

// ---------------- grouped fused gate+up GEMM (r6 champion + XCD swizzle) ----------------
// 128-row x 64-col tile; K = HDIM, NT = 16 K-steps. H[slot][I] = silu(g)*u bf16.
__global__ __launch_bounds__(256)
void gemm_gu(const u16* __restrict__ A,            // x_bf [T][H]
             const u16* __restrict__ WG,           // [16][512][1024]
             const u16* __restrict__ WU,
             const u16* __restrict__ SWG,          // [2*512][1024]
             const u16* __restrict__ SWU,
             u16* __restrict__ H,                  // [NSLOT][512]
             const int* __restrict__ offs,
             const int* __restrict__ rowmap,
             const int* __restrict__ rbGroup,
             const int* __restrict__ rbRow0) {
    // XCD-chunked bijective swizzle: 1280 blocks, 1280%8==0
    int b = blockIdx.x;
    int L = (b & 7) * 160 + (b >> 3);
    int cb = L & 7;            // 8 col-blocks of 64
    int rb = L >> 3;           // 0..159
    int g = rbGroup[rb];
    if (g < 0) return;
    int row0 = rbRow0[rb];
    int mend = offs[g + 1];
    int col0 = cb * 64;
    long wb = (long)((g < 16) ? g : (g - 16)) * IDIM * HDIM;
    const u16* Bg = (g < 16) ? WG + wb : SWG + wb;
    const u16* Bu = (g < 16) ? WU + wb : SWU + wb;

    __shared__ u16 sA[2][128 * 64];
    __shared__ u16 sBg[2][64 * 64];
    __shared__ u16 sBu[2][64 * 64];

    int tid = threadIdx.x;
    int lane = tid & 63;
    int w = tid >> 6;
    int wr = (w >> 1) * 64, wc = (w & 1) * 32;
    int lhi = lane >> 4, llo = lane & 15;
    int swz = llo & 7;

    // hoisted staging pointers (swizzled global source, linear LDS dest)
    const u16* pA[4]; int dA[4];
#pragma unroll
    for (int c = 0; c < 4; ++c) {
        int idx = c * 256 + tid;
        int r = idx >> 3, ch = idx & 7;
        int grow = row0 + r;
        int ar = rowmap[(grow < mend) ? grow : row0];
        pA[c] = A + (long)ar * HDIM + ((ch ^ (r & 7)) * 8);
        dA[c] = idx * 8;
    }
    const u16* pBg[2]; const u16* pBu[2]; int dB[2];
#pragma unroll
    for (int c = 0; c < 2; ++c) {
        int idx = c * 256 + tid;
        int r = idx >> 3, ch = idx & 7;
        long boff = (long)(col0 + r) * HDIM + ((ch ^ (r & 7)) * 8);
        pBg[c] = Bg + boff; pBu[c] = Bu + boff;
        dB[c] = idx * 8;
    }

    f32x4 accg[4][2], accu[4][2];
#pragma unroll
    for (int m = 0; m < 4; ++m)
#pragma unroll
        for (int n = 0; n < 2; ++n) {
            f32x4 z = {0.f, 0.f, 0.f, 0.f};
            accg[m][n] = z; accu[m][n] = z;
        }

    auto STAGE = [&](int buf) {
#pragma unroll
        for (int c = 0; c < 4; ++c) { async16(&sA[buf][dA[c]], pA[c]); pA[c] += 64; }
#pragma unroll
        for (int c = 0; c < 2; ++c) {
            async16(&sBg[buf][dB[c]], pBg[c]); pBg[c] += 64;
            async16(&sBu[buf][dB[c]], pBu[c]); pBu[c] += 64;
        }
    };
    auto COMPUTE = [&](int buf) {
#pragma unroll
        for (int kk = 0; kk < 2; ++kk) {
            int p = ((kk * 4 + lhi) ^ swz) * 8;   // swizzled chunk position
            bfrag a[4], bg[2], bu[2];
#pragma unroll
            for (int m = 0; m < 4; ++m)
                a[m] = *(const bfrag*)&sA[buf][(wr + m * 16 + llo) * 64 + p];
#pragma unroll
            for (int n = 0; n < 2; ++n) {
                bg[n] = *(const bfrag*)&sBg[buf][(wc + n * 16 + llo) * 64 + p];
                bu[n] = *(const bfrag*)&sBu[buf][(wc + n * 16 + llo) * 64 + p];
            }
#pragma unroll
            for (int m = 0; m < 4; ++m)
#pragma unroll
                for (int n = 0; n < 2; ++n) {
                    accg[m][n] = __builtin_amdgcn_mfma_f32_16x16x32_bf16(a[m], bg[n], accg[m][n], 0, 0, 0);
                    accu[m][n] = __builtin_amdgcn_mfma_f32_16x16x32_bf16(a[m], bu[n], accu[m][n], 0, 0, 0);
                }
        }
    };

    // NT = 16: prologue + 7x unrolled-pair + tail pair
    STAGE(0);
#pragma unroll 1
    for (int t = 0; t < 14; t += 2) {
        STAGE(1); SYNCN(8); COMPUTE(0); BAR2();
        STAGE(0); SYNCN(8); COMPUTE(1); BAR2();
    }
    STAGE(1); SYNCN(8); COMPUTE(0); BAR2();
    SYNCN(0); COMPUTE(1);

#pragma unroll
    for (int m = 0; m < 4; ++m) {
        int rbase = row0 + wr + m * 16 + lhi * 4;
#pragma unroll
        for (int n = 0; n < 2; ++n) {
            int col = col0 + wc + n * 16 + llo;
#pragma unroll
            for (int i = 0; i < 4; ++i) {
                int grow = rbase + i;
                if (grow >= mend) continue;
                float gv = accg[m][n][i], uv = accu[m][n][i];
                float hv = gv / (1.f + __expf(-gv)) * uv;
                H[(long)grow * IDIM + col] = f2bf(hv);
            }
        }
    }
}

// ---------------- grouped down GEMM (r6 champion + XCD swizzle) ----------------
// NT = IDIM/64 = 8 K-steps.
__global__ __launch_bounds__(256)
void gemm_down(const u16* __restrict__ Hbuf,       // [NSLOT][512]
               const u16* __restrict__ WD,         // [16][1024][512]
               const u16* __restrict__ SWD,        // [2][1024][512]
               u16* __restrict__ EO,               // [NSLOT][1024]
               const int* __restrict__ offs,
               const int* __restrict__ rbGroup,
               const int* __restrict__ rbRow0) {
    int b = blockIdx.x;
    int L = (b & 7) * 160 + (b >> 3);
    int cb = L & 7;            // 8 col-blocks of 128
    int rb = L >> 3;
    int g = rbGroup[rb];
    if (g < 0) return;
    int row0 = rbRow0[rb];
    int mend = offs[g + 1];
    int col0 = cb * 128;
    long wb = (long)((g < 16) ? g : (g - 16)) * HDIM * IDIM;
    const u16* B = (g < 16) ? WD + wb : SWD + wb;

    __shared__ u16 sA[2][128 * 64];
    __shared__ u16 sB[2][128 * 64];

    int tid = threadIdx.x;
    int lane = tid & 63;
    int w = tid >> 6;
    int wr = (w >> 1) * 64, wc = (w & 1) * 64;
    int lhi = lane >> 4, llo = lane & 15;
    int swz = llo & 7;

    const u16* pA[4]; const u16* pB[4]; int dd[4];
#pragma unroll
    for (int c = 0; c < 4; ++c) {
        int idx = c * 256 + tid;
        int r = idx >> 3, ch = idx & 7;
        int grow = row0 + r;
        int ar = (grow < mend) ? grow : row0;
        int chs = (ch ^ (r & 7)) * 8;
        pA[c] = Hbuf + (long)ar * IDIM + chs;
        pB[c] = B + (long)(col0 + r) * IDIM + chs;
        dd[c] = idx * 8;
    }

    f32x4 acc[4][4];
#pragma unroll
    for (int m = 0; m < 4; ++m)
#pragma unroll
        for (int n = 0; n < 4; ++n) { f32x4 z = {0.f, 0.f, 0.f, 0.f}; acc[m][n] = z; }

    auto STAGE = [&](int buf) {
#pragma unroll
        for (int c = 0; c < 4; ++c) {
            async16(&sA[buf][dd[c]], pA[c]); pA[c] += 64;
            async16(&sB[buf][dd[c]], pB[c]); pB[c] += 64;
        }
    };
    auto COMPUTE = [&](int buf) {
#pragma unroll
        for (int kk = 0; kk < 2; ++kk) {
            int p = ((kk * 4 + lhi) ^ swz) * 8;
            bfrag a[4], b2[4];
#pragma unroll
            for (int m = 0; m < 4; ++m)
                a[m] = *(const bfrag*)&sA[buf][(wr + m * 16 + llo) * 64 + p];
#pragma unroll
            for (int n = 0; n < 4; ++n)
                b2[n] = *(const bfrag*)&sB[buf][(wc + n * 16 + llo) * 64 + p];
#pragma unroll
            for (int m = 0; m < 4; ++m)
#pragma unroll
                for (int n = 0; n < 4; ++n)
                    acc[m][n] = __builtin_amdgcn_mfma_f32_16x16x32_bf16(a[m], b2[n], acc[m][n], 0, 0, 0);
        }
    };

    // NT = 8: prologue + 3x pair + tail pair
    STAGE(0);
#pragma unroll 1
    for (int t = 0; t < 6; t += 2) {
        STAGE(1); SYNCN(8); COMPUTE(0); BAR2();
        STAGE(0); SYNCN(8); COMPUTE(1); BAR2();
    }
    STAGE(1); SYNCN(8); COMPUTE(0); BAR2();
    SYNCN(0); COMPUTE(1);

#pragma unroll
    for (int m = 0; m < 4; ++m) {
        int rbase = row0 + wr + m * 16 + lhi * 4;
#pragma unroll
        for (int n = 0; n < 4; ++n) {
            int col = col0 + wc + n * 16 + llo;
#pragma unroll
            for (int i = 0; i < 4; ++i) {
                int grow = rbase + i;
                if (grow >= mend) continue;
                EO[(long)grow * HDIM + col] = f2bf(acc[m][n][i]);
            }
        }
    }
}

// ---------------- combine: out = w0*eo[r0] + w1*eo[r1] + eo[sh0] + eo[sh1] ----------------
__global__ __launch_bounds__(256) void combine_k(float* __restrict__ out,
                                                 const u16* __restrict__ eo,
                                                 const int* __restrict__ invmap,
                                                 const float* __restrict__ wts) {
    int t = blockIdx.x;
    int h = threadIdx.x * 4;
    int r0 = invmap[t * 2], r1 = invmap[t * 2 + 1];
    float w0 = wts[t * 2], w1 = wts[t * 2 + 1];
    int s0 = 8192 + t, s1 = 8192 + T_TOK + t;
    ushort4 a = *(const ushort4*)(eo + (long)r0 * HDIM + h);
    ushort4 b = *(const ushort4*)(eo + (long)r1 * HDIM + h);
    ushort4 c = *(const ushort4*)(eo + (long)s0 * HDIM + h);
    ushort4 d = *(const ushort4*)(eo + (long)s1 * HDIM + h);
    float4 o;
    o.x = w0 * bf2f(a.x) + w1 * bf2f(b.x) + bf2f(c.x) + bf2f(d.x);
    o.y = w0 * bf2f(a.y) + w1 * bf2f(b.y) + bf2f(c.y) + bf2f(d.y);
    o.z = w0 * bf2f(a.z) + w1 * bf2f(b.z) + bf2f(c.z) + bf2f(d.z);
    o.w = w0 * bf2f(a.w) + w1 * bf2f(b.w) + bf2f(c.w) + bf2f(d.w);
    *(float4*)(out + (long)t * HDIM + h) = o;
}

extern "C" void kernel_launch(void* const* d_in, const int* in_sizes, int n_in,
                              void* d_out, int out_size, void* d_ws, size_t ws_size,
                              hipStream_t stream) {
    const float* x    = (const float*)d_in[0];
    const float* rw   = (const float*)d_in[1];
    const float* bias = (const float*)d_in[2];
    const float* wg   = (const float*)d_in[3];
    const float* wu   = (const float*)d_in[4];
    const float* wd   = (const float*)d_in[5];
    const float* swg  = (const float*)d_in[6];
    const float* swu  = (const float*)d_in[7];
    const float* swd  = (const float*)d_in[8];
    float* out = (float*)d_out;

    char* ws = (char*)d_ws;
    size_t o = 0;
    auto alloc = [&](size_t bytes) -> void* {
        void* p = ws + o;
        o += (bytes + 255) & ~(size_t)255;
        return p;
    };
    u16* x_bf = (u16*)alloc((size_t)T_TOK * HDIM * 2);
    u16* WtG  = (u16*)alloc((size_t)NEXP * IDIM * HDIM * 2);   // 16 MB
    u16* WtU  = (u16*)alloc((size_t)NEXP * IDIM * HDIM * 2);   // 16 MB (contiguous after WtG)
    u16* WtD  = (u16*)alloc((size_t)NEXP * HDIM * IDIM * 2);
    u16* SWtG = (u16*)alloc((size_t)2 * IDIM * HDIM * 2);
    u16* SWtU = (u16*)alloc((size_t)2 * IDIM * HDIM * 2);
    u16* SWtD = (u16*)alloc((size_t)2 * HDIM * IDIM * 2);
    u16* Hbuf = (u16*)alloc((size_t)NSLOT * IDIM * 2);         // 16 MB
    int*   sel     = (int*)alloc((size_t)T_TOK * 2 * 4);
    float* wts     = (float*)alloc((size_t)T_TOK * 2 * 4);
    int*   invmap  = (int*)alloc((size_t)T_TOK * 2 * 4);
    int*   rowmap  = (int*)alloc((size_t)NSLOT * 4);
    int*   offs    = (int*)alloc((NGRP + 1) * 4);
    int*   rbGroup = (int*)alloc(MAXRB * 4);
    int*   rbRow0  = (int*)alloc(MAXRB * 4);
    // EO (32 MB) aliases WtG+WtU, which are dead after gemm_gu completes.
    u16* EO = WtG;

    // 1: all weight transposes + router + x->bf16 in ONE launch
    prep_k<<<dim3(1728 + 1024), 256, 0, stream>>>(
        x, rw, bias, wg, wu, wd, swg, swu, swd,
        WtG, WtU, WtD, SWtG, SWtU, SWtD, sel, wts, x_bf);

    // 2: routing tables
    route_build_k<<<dim3(1), 1024, 0, stream>>>(sel, offs, rowmap, invmap, rbGroup, rbRow0);

    // 3: fused gate+up (flattened grid, XCD swizzle)
    gemm_gu<<<dim3(8 * MAXRB), 256, 0, stream>>>(
        x_bf, WtG, WtU, SWtG, SWtU, Hbuf, offs, rowmap, rbGroup, rbRow0);

    // 4: down projection (flattened grid, XCD swizzle)
    gemm_down<<<dim3(8 * MAXRB), 256, 0, stream>>>(
        Hbuf, WtD, SWtD, EO, offs, rbGroup, rbRow0);

    // 5: combine
    combine_k<<<dim3(T_TOK), 256, 0, stream>>>(out, EO, invmap, wts);
}

// Round 19
// 153.944 us; speedup vs baseline: 1.0204x; 1.0204x over previous
//
#include <hip/hip_runtime.h>
#include <math.h>

#define T_TOK 4096
#define HDIM  1024
#define NEXP  16
#define IDIM  512
#define NSLOT 16384          // 8192 routed + 2*4096 shared-pseudo
#define NGRP  18
#define MAXRB 160            // 128-row blocks

typedef unsigned int u32;
typedef unsigned short u16;
typedef __attribute__((ext_vector_type(8))) short bfrag;   // 8 bf16 (4 VGPRs)
typedef __attribute__((ext_vector_type(4))) float f32x4;

__device__ __forceinline__ u16 f2bf(float f) {
    union { float f; u32 u; } c; c.f = f;
    u32 u = c.u;
    u32 r = u + 0x7fffu + ((u >> 16) & 1u);   // RNE
    return (u16)(r >> 16);
}
__device__ __forceinline__ float bf2f(u16 h) {
    union { u32 u; float f; } c; c.u = ((u32)h) << 16;
    return c.f;
}

__device__ __forceinline__ void async16(void* lds, const void* g) {
    __builtin_amdgcn_global_load_lds((__attribute__((address_space(1))) void*)(g),
                                     (__attribute__((address_space(3))) void*)(lds),
                                     16, 0, 0);
}

// counted-wait + raw barrier (never drain vmcnt to 0 inside the K-loop)
#define SYNCN(n) do { \
    asm volatile("s_waitcnt vmcnt(" #n ")" ::: "memory"); \
    __builtin_amdgcn_s_barrier(); \
    __builtin_amdgcn_sched_barrier(0); \
} while (0)
#define BAR2() do { \
    __builtin_amdgcn_s_barrier(); \
    __builtin_amdgcn_sched_barrier(0); \
} while (0)

// ---------------- fused prep: weight transposes (128x128 macro-tiles, 16-deep MLP)
// + router + x->bf16, ONE launch ----------------
// Blocks 0..1727: transpose macro-tiles. Blocks 1728..2751: router (4 tokens each).
__device__ __forceinline__ void transpose_tile4(const float* __restrict__ src,
                                                u16* __restrict__ dst,
                                                int R, int C, long base, int bx, int by) {
    __shared__ u16 tileT[4][32][132];
    int c0 = bx * 128, r0 = by * 128;
    int t = threadIdx.x;
    int rr = t >> 3;             // 0..31
    int c4 = (t & 7) * 4;        // 0,4,...,28
    // issue all 16 loads up-front (16-deep MLP)
    float4 v[4][4];
#pragma unroll
    for (int s = 0; s < 4; ++s)
#pragma unroll
        for (int p = 0; p < 4; ++p) {
            int r = p * 32 + rr;
            v[s][p] = *(const float4*)(src + base + (long)(r0 + r) * C + c0 + s * 32 + c4);
        }
#pragma unroll
    for (int s = 0; s < 4; ++s)
#pragma unroll
        for (int p = 0; p < 4; ++p) {
            int r = p * 32 + rr;
            tileT[s][c4 + 0][r] = f2bf(v[s][p].x);
            tileT[s][c4 + 1][r] = f2bf(v[s][p].y);
            tileT[s][c4 + 2][r] = f2bf(v[s][p].z);
            tileT[s][c4 + 3][r] = f2bf(v[s][p].w);
        }
    __syncthreads();
    int cc = t >> 5;             // 0..7
    int r4 = (t & 31) * 4;
#pragma unroll
    for (int s = 0; s < 4; ++s)
#pragma unroll
        for (int q = 0; q < 4; ++q) {
            int c = q * 8 + cc;
            ushort4 o;
            o.x = tileT[s][c][r4];     o.y = tileT[s][c][r4 + 1];
            o.z = tileT[s][c][r4 + 2]; o.w = tileT[s][c][r4 + 3];
            *(ushort4*)(dst + base + (long)(c0 + s * 32 + c) * R + r0 + r4) = o;
        }
}

__global__ __launch_bounds__(256)
void prep_k(const float* __restrict__ x, const float* __restrict__ rw,
            const float* __restrict__ bias,
            const float* __restrict__ wg, const float* __restrict__ wu,
            const float* __restrict__ wd, const float* __restrict__ swg,
            const float* __restrict__ swu, const float* __restrict__ swd,
            u16* __restrict__ WtG, u16* __restrict__ WtU, u16* __restrict__ WtD,
            u16* __restrict__ SWtG, u16* __restrict__ SWtU, u16* __restrict__ SWtD,
            int* __restrict__ sel, float* __restrict__ wts, u16* __restrict__ x_bf) {
    int b = blockIdx.x;
    if (b < 512) {                        // wg: 16 x [1024][512] -> [512][1024]; 32 tiles/e (4C x 8R)
        int e = b >> 5, t = b & 31;
        transpose_tile4(wg, WtG, HDIM, IDIM, (long)e * HDIM * IDIM, t & 3, t >> 2);
        return;
    } else if (b < 1024) {                // wu
        int bb = b - 512, e = bb >> 5, t = bb & 31;
        transpose_tile4(wu, WtU, HDIM, IDIM, (long)e * HDIM * IDIM, t & 3, t >> 2);
        return;
    } else if (b < 1536) {                // wd: 16 x [512][1024] -> [1024][512]; 32 tiles/e (8C x 4R)
        int bb = b - 1024, e = bb >> 5, t = bb & 31;
        transpose_tile4(wd, WtD, IDIM, HDIM, (long)e * IDIM * HDIM, t & 7, t >> 3);
        return;
    } else if (b < 1600) {                // swg: [1024][1024]; 64 tiles (8C x 8R)
        int t = b - 1536;
        transpose_tile4(swg, SWtG, HDIM, 2 * IDIM, 0, t & 7, t >> 3);
        return;
    } else if (b < 1664) {                // swu
        int t = b - 1600;
        transpose_tile4(swu, SWtU, HDIM, 2 * IDIM, 0, t & 7, t >> 3);
        return;
    } else if (b < 1728) {                // swd as 2 pseudo [512][1024] -> [1024][512]; 32 tiles each
        int t = b - 1664, z = t >> 5, tt = t & 31;
        transpose_tile4(swd, SWtD, IDIM, HDIM, (long)z * IDIM * HDIM, tt & 7, tt >> 3);
        return;
    }
    // ---- router part: blocks 1728..2751, one wave per token ----
    int tid = threadIdx.x;
    int wv = tid >> 6;
    int lane = tid & 63;
    int t = (b - 1728) * 4 + wv;

    // emit bf16 row (coalesced: 64 lanes x 16B)
    const float4* xr4 = (const float4*)(x + (long)t * HDIM);
    ushort4* xb4 = (ushort4*)(x_bf + (long)t * HDIM);
#pragma unroll
    for (int j = 0; j < 4; ++j) {
        float4 v = xr4[lane + j * 64];
        ushort4 ov;
        ov.x = f2bf(v.x); ov.y = f2bf(v.y); ov.z = f2bf(v.z); ov.w = f2bf(v.w);
        xb4[lane + j * 64] = ov;
    }

    int e = lane & 15, hc = lane >> 4;
    const float* xr = x + (long)t * HDIM + hc * 256;
    const float* rp = rw + (long)hc * 256 * NEXP + e;
    float acc = 0.f;
#pragma unroll 4
    for (int i = 0; i < 64; ++i) {
        float4 xv = *(const float4*)(xr + i * 4);
        acc += xv.x * rp[(i * 4 + 0) * NEXP] + xv.y * rp[(i * 4 + 1) * NEXP]
             + xv.z * rp[(i * 4 + 2) * NEXP] + xv.w * rp[(i * 4 + 3) * NEXP];
    }
    acc += __shfl_down(acc, 16);
    acc += __shfl_down(acc, 32);
    float sc = 1.f / (1.f + __expf(-acc));     // valid on lanes 0..15
    float v = sc + bias[e];
    int i0 = -1, i1 = -1;
    float v0 = -1e30f, v1 = -1e30f, s0 = 0.f, s1 = 0.f;
#pragma unroll
    for (int j = 0; j < 16; ++j) {
        float vj = __shfl(v, j);
        float scj = __shfl(sc, j);
        if (vj > v0) { v1 = v0; i1 = i0; s1 = s0; v0 = vj; i0 = j; s0 = scj; }
        else if (vj > v1) { v1 = vj; i1 = j; s1 = scj; }
    }
    if (lane == 0) {
        float nrm = s0 + s1 + 1e-20f;
        sel[t * 2] = i0; sel[t * 2 + 1] = i1;
        wts[t * 2] = s0 / nrm; wts[t * 2 + 1] = s1 / nrm;
    }
}

// ---------------- routing build: single block, LDS atomics only ----------------
__global__ __launch_bounds__(1024) void route_build_k(const int* __restrict__ sel,
                                                      int* __restrict__ offs,
                                                      int* __restrict__ rowmap,
                                                      int* __restrict__ invmap,
                                                      int* __restrict__ rbGroup,
                                                      int* __restrict__ rbRow0) {
    __shared__ int hist[NEXP];
    __shared__ int cur[NEXP];
    int tid = threadIdx.x;
    if (tid < NEXP) hist[tid] = 0;
    __syncthreads();
    for (int i = tid; i < T_TOK * 2; i += 1024)
        atomicAdd(&hist[sel[i]], 1);
    __syncthreads();
    if (tid == 0) {
        int a = 0;
        for (int g = 0; g < NEXP; ++g) { cur[g] = a; offs[g] = a; a += hist[g]; }
        offs[16] = 8192;
        offs[17] = 8192 + T_TOK;
        offs[18] = 8192 + 2 * T_TOK;
        int rb = 0;
        for (int g = 0; g < NGRP; ++g)
            for (int r0 = offs[g]; r0 < offs[g + 1]; r0 += 128) {
                rbGroup[rb] = g; rbRow0[rb] = r0; ++rb;
            }
        for (; rb < MAXRB; ++rb) rbGroup[rb] = -1;
    }
    __syncthreads();
    for (int i = tid; i < T_TOK * 2; i += 1024) {
        int g = sel[i];
        int slot = atomicAdd(&cur[g], 1);
        rowmap[slot] = i >> 1;
        invmap[i] = slot;
    }
    for (int i = tid; i < T_TOK; i += 1024) {
        rowmap[8192 + i] = i;
        rowmap[8192 + T_TOK + i] = i;
    }
}

// ---------------- grouped fused gate+up GEMM (r6 champion + XCD swizzle) ----------------
// 128-row x 64-col tile; K = HDIM, NT = 16 K-steps. H[slot][I] = silu(g)*u bf16.
__global__ __launch_bounds__(256)
void gemm_gu(const u16* __restrict__ A,            // x_bf [T][H]
             const u16* __restrict__ WG,           // [16][512][1024]
             const u16* __restrict__ WU,
             const u16* __restrict__ SWG,          // [2*512][1024]
             const u16* __restrict__ SWU,
             u16* __restrict__ H,                  // [NSLOT][512]
             const int* __restrict__ offs,
             const int* __restrict__ rowmap,
             const int* __restrict__ rbGroup,
             const int* __restrict__ rbRow0) {
    // XCD-chunked bijective swizzle: 1280 blocks, 1280%8==0
    int b = blockIdx.x;
    int L = (b & 7) * 160 + (b >> 3);
    int cb = L & 7;            // 8 col-blocks of 64
    int rb = L >> 3;           // 0..159
    int g = rbGroup[rb];
    if (g < 0) return;
    int row0 = rbRow0[rb];
    int mend = offs[g + 1];
    int col0 = cb * 64;
    long wb = (long)((g < 16) ? g : (g - 16)) * IDIM * HDIM;
    const u16* Bg = (g < 16) ? WG + wb : SWG + wb;
    const u16* Bu = (g < 16) ? WU + wb : SWU + wb;

    __shared__ u16 sA[2][128 * 64];
    __shared__ u16 sBg[2][64 * 64];
    __shared__ u16 sBu[2][64 * 64];

    int tid = threadIdx.x;
    int lane = tid & 63;
    int w = tid >> 6;
    int wr = (w >> 1) * 64, wc = (w & 1) * 32;
    int lhi = lane >> 4, llo = lane & 15;
    int swz = llo & 7;

    // hoisted staging pointers (swizzled global source, linear LDS dest)
    const u16* pA[4]; int dA[4];
#pragma unroll
    for (int c = 0; c < 4; ++c) {
        int idx = c * 256 + tid;
        int r = idx >> 3, ch = idx & 7;
        int grow = row0 + r;
        int ar = rowmap[(grow < mend) ? grow : row0];
        pA[c] = A + (long)ar * HDIM + ((ch ^ (r & 7)) * 8);
        dA[c] = idx * 8;
    }
    const u16* pBg[2]; const u16* pBu[2]; int dB[2];
#pragma unroll
    for (int c = 0; c < 2; ++c) {
        int idx = c * 256 + tid;
        int r = idx >> 3, ch = idx & 7;
        long boff = (long)(col0 + r) * HDIM + ((ch ^ (r & 7)) * 8);
        pBg[c] = Bg + boff; pBu[c] = Bu + boff;
        dB[c] = idx * 8;
    }

    f32x4 accg[4][2], accu[4][2];
#pragma unroll
    for (int m = 0; m < 4; ++m)
#pragma unroll
        for (int n = 0; n < 2; ++n) {
            f32x4 z = {0.f, 0.f, 0.f, 0.f};
            accg[m][n] = z; accu[m][n] = z;
        }

    auto STAGE = [&](int buf) {
#pragma unroll
        for (int c = 0; c < 4; ++c) { async16(&sA[buf][dA[c]], pA[c]); pA[c] += 64; }
#pragma unroll
        for (int c = 0; c < 2; ++c) {
            async16(&sBg[buf][dB[c]], pBg[c]); pBg[c] += 64;
            async16(&sBu[buf][dB[c]], pBu[c]); pBu[c] += 64;
        }
    };
    auto COMPUTE = [&](int buf) {
#pragma unroll
        for (int kk = 0; kk < 2; ++kk) {
            int p = ((kk * 4 + lhi) ^ swz) * 8;   // swizzled chunk position
            bfrag a[4], bg[2], bu[2];
#pragma unroll
            for (int m = 0; m < 4; ++m)
                a[m] = *(const bfrag*)&sA[buf][(wr + m * 16 + llo) * 64 + p];
#pragma unroll
            for (int n = 0; n < 2; ++n) {
                bg[n] = *(const bfrag*)&sBg[buf][(wc + n * 16 + llo) * 64 + p];
                bu[n] = *(const bfrag*)&sBu[buf][(wc + n * 16 + llo) * 64 + p];
            }
#pragma unroll
            for (int m = 0; m < 4; ++m)
#pragma unroll
                for (int n = 0; n < 2; ++n) {
                    accg[m][n] = __builtin_amdgcn_mfma_f32_16x16x32_bf16(a[m], bg[n], accg[m][n], 0, 0, 0);
                    accu[m][n] = __builtin_amdgcn_mfma_f32_16x16x32_bf16(a[m], bu[n], accu[m][n], 0, 0, 0);
                }
        }
    };

    // NT = 16: prologue + 7x unrolled-pair + tail pair
    STAGE(0);
#pragma unroll 1
    for (int t = 0; t < 14; t += 2) {
        STAGE(1); SYNCN(8); COMPUTE(0); BAR2();
        STAGE(0); SYNCN(8); COMPUTE(1); BAR2();
    }
    STAGE(1); SYNCN(8); COMPUTE(0); BAR2();
    SYNCN(0); COMPUTE(1);

#pragma unroll
    for (int m = 0; m < 4; ++m) {
        int rbase = row0 + wr + m * 16 + lhi * 4;
#pragma unroll
        for (int n = 0; n < 2; ++n) {
            int col = col0 + wc + n * 16 + llo;
#pragma unroll
            for (int i = 0; i < 4; ++i) {
                int grow = rbase + i;
                if (grow >= mend) continue;
                float gv = accg[m][n][i], uv = accu[m][n][i];
                float hv = gv / (1.f + __expf(-gv)) * uv;
                H[(long)grow * IDIM + col] = f2bf(hv);
            }
        }
    }
}

// ---------------- grouped down GEMM (r6 champion + XCD swizzle) ----------------
// NT = IDIM/64 = 8 K-steps.
__global__ __launch_bounds__(256)
void gemm_down(const u16* __restrict__ Hbuf,       // [NSLOT][512]
               const u16* __restrict__ WD,         // [16][1024][512]
               const u16* __restrict__ SWD,        // [2][1024][512]
               u16* __restrict__ EO,               // [NSLOT][1024]
               const int* __restrict__ offs,
               const int* __restrict__ rbGroup,
               const int* __restrict__ rbRow0) {
    int b = blockIdx.x;
    int L = (b & 7) * 160 + (b >> 3);
    int cb = L & 7;            // 8 col-blocks of 128
    int rb = L >> 3;
    int g = rbGroup[rb];
    if (g < 0) return;
    int row0 = rbRow0[rb];
    int mend = offs[g + 1];
    int col0 = cb * 128;
    long wb = (long)((g < 16) ? g : (g - 16)) * HDIM * IDIM;
    const u16* B = (g < 16) ? WD + wb : SWD + wb;

    __shared__ u16 sA[2][128 * 64];
    __shared__ u16 sB[2][128 * 64];

    int tid = threadIdx.x;
    int lane = tid & 63;
    int w = tid >> 6;
    int wr = (w >> 1) * 64, wc = (w & 1) * 64;
    int lhi = lane >> 4, llo = lane & 15;
    int swz = llo & 7;

    const u16* pA[4]; const u16* pB[4]; int dd[4];
#pragma unroll
    for (int c = 0; c < 4; ++c) {
        int idx = c * 256 + tid;
        int r = idx >> 3, ch = idx & 7;
        int grow = row0 + r;
        int ar = (grow < mend) ? grow : row0;
        int chs = (ch ^ (r & 7)) * 8;
        pA[c] = Hbuf + (long)ar * IDIM + chs;
        pB[c] = B + (long)(col0 + r) * IDIM + chs;
        dd[c] = idx * 8;
    }

    f32x4 acc[4][4];
#pragma unroll
    for (int m = 0; m < 4; ++m)
#pragma unroll
        for (int n = 0; n < 4; ++n) { f32x4 z = {0.f, 0.f, 0.f, 0.f}; acc[m][n] = z; }

    auto STAGE = [&](int buf) {
#pragma unroll
        for (int c = 0; c < 4; ++c) {
            async16(&sA[buf][dd[c]], pA[c]); pA[c] += 64;
            async16(&sB[buf][dd[c]], pB[c]); pB[c] += 64;
        }
    };
    auto COMPUTE = [&](int buf) {
#pragma unroll
        for (int kk = 0; kk < 2; ++kk) {
            int p = ((kk * 4 + lhi) ^ swz) * 8;
            bfrag a[4], b2[4];
#pragma unroll
            for (int m = 0; m < 4; ++m)
                a[m] = *(const bfrag*)&sA[buf][(wr + m * 16 + llo) * 64 + p];
#pragma unroll
            for (int n = 0; n < 4; ++n)
                b2[n] = *(const bfrag*)&sB[buf][(wc + n * 16 + llo) * 64 + p];
#pragma unroll
            for (int m = 0; m < 4; ++m)
#pragma unroll
                for (int n = 0; n < 4; ++n)
                    acc[m][n] = __builtin_amdgcn_mfma_f32_16x16x32_bf16(a[m], b2[n], acc[m][n], 0, 0, 0);
        }
    };

    // NT = 8: prologue + 3x pair + tail pair
    STAGE(0);
#pragma unroll 1
    for (int t = 0; t < 6; t += 2) {
        STAGE(1); SYNCN(8); COMPUTE(0); BAR2();
        STAGE(0); SYNCN(8); COMPUTE(1); BAR2();
    }
    STAGE(1); SYNCN(8); COMPUTE(0); BAR2();
    SYNCN(0); COMPUTE(1);

#pragma unroll
    for (int m = 0; m < 4; ++m) {
        int rbase = row0 + wr + m * 16 + lhi * 4;
#pragma unroll
        for (int n = 0; n < 4; ++n) {
            int col = col0 + wc + n * 16 + llo;
#pragma unroll
            for (int i = 0; i < 4; ++i) {
                int grow = rbase + i;
                if (grow >= mend) continue;
                EO[(long)grow * HDIM + col] = f2bf(acc[m][n][i]);
            }
        }
    }
}

// ---------------- combine: out = w0*eo[r0] + w1*eo[r1] + eo[sh0] + eo[sh1] ----------------
__global__ __launch_bounds__(256) void combine_k(float* __restrict__ out,
                                                 const u16* __restrict__ eo,
                                                 const int* __restrict__ invmap,
                                                 const float* __restrict__ wts) {
    int t = blockIdx.x;
    int h = threadIdx.x * 4;
    int r0 = invmap[t * 2], r1 = invmap[t * 2 + 1];
    float w0 = wts[t * 2], w1 = wts[t * 2 + 1];
    int s0 = 8192 + t, s1 = 8192 + T_TOK + t;
    ushort4 a = *(const ushort4*)(eo + (long)r0 * HDIM + h);
    ushort4 b = *(const ushort4*)(eo + (long)r1 * HDIM + h);
    ushort4 c = *(const ushort4*)(eo + (long)s0 * HDIM + h);
    ushort4 d = *(const ushort4*)(eo + (long)s1 * HDIM + h);
    float4 o;
    o.x = w0 * bf2f(a.x) + w1 * bf2f(b.x) + bf2f(c.x) + bf2f(d.x);
    o.y = w0 * bf2f(a.y) + w1 * bf2f(b.y) + bf2f(c.y) + bf2f(d.y);
    o.z = w0 * bf2f(a.z) + w1 * bf2f(b.z) + bf2f(c.z) + bf2f(d.z);
    o.w = w0 * bf2f(a.w) + w1 * bf2f(b.w) + bf2f(c.w) + bf2f(d.w);
    *(float4*)(out + (long)t * HDIM + h) = o;
}

extern "C" void kernel_launch(void* const* d_in, const int* in_sizes, int n_in,
                              void* d_out, int out_size, void* d_ws, size_t ws_size,
                              hipStream_t stream) {
    const float* x    = (const float*)d_in[0];
    const float* rw   = (const float*)d_in[1];
    const float* bias = (const float*)d_in[2];
    const float* wg   = (const float*)d_in[3];
    const float* wu   = (const float*)d_in[4];
    const float* wd   = (const float*)d_in[5];
    const float* swg  = (const float*)d_in[6];
    const float* swu  = (const float*)d_in[7];
    const float* swd  = (const float*)d_in[8];
    float* out = (float*)d_out;

    char* ws = (char*)d_ws;
    size_t o = 0;
    auto alloc = [&](size_t bytes) -> void* {
        void* p = ws + o;
        o += (bytes + 255) & ~(size_t)255;
        return p;
    };
    u16* x_bf = (u16*)alloc((size_t)T_TOK * HDIM * 2);
    u16* WtG  = (u16*)alloc((size_t)NEXP * IDIM * HDIM * 2);   // 16 MB
    u16* WtU  = (u16*)alloc((size_t)NEXP * IDIM * HDIM * 2);   // 16 MB (contiguous after WtG)
    u16* WtD  = (u16*)alloc((size_t)NEXP * HDIM * IDIM * 2);
    u16* SWtG = (u16*)alloc((size_t)2 * IDIM * HDIM * 2);
    u16* SWtU = (u16*)alloc((size_t)2 * IDIM * HDIM * 2);
    u16* SWtD = (u16*)alloc((size_t)2 * HDIM * IDIM * 2);
    u16* Hbuf = (u16*)alloc((size_t)NSLOT * IDIM * 2);         // 16 MB
    int*   sel     = (int*)alloc((size_t)T_TOK * 2 * 4);
    float* wts     = (float*)alloc((size_t)T_TOK * 2 * 4);
    int*   invmap  = (int*)alloc((size_t)T_TOK * 2 * 4);
    int*   rowmap  = (int*)alloc((size_t)NSLOT * 4);
    int*   offs    = (int*)alloc((NGRP + 1) * 4);
    int*   rbGroup = (int*)alloc(MAXRB * 4);
    int*   rbRow0  = (int*)alloc(MAXRB * 4);
    // EO (32 MB) aliases WtG+WtU, which are dead after gemm_gu completes.
    u16* EO = WtG;

    // 1: all weight transposes + router + x->bf16 in ONE launch
    prep_k<<<dim3(1728 + 1024), 256, 0, stream>>>(
        x, rw, bias, wg, wu, wd, swg, swu, swd,
        WtG, WtU, WtD, SWtG, SWtU, SWtD, sel, wts, x_bf);

    // 2: routing tables
    route_build_k<<<dim3(1), 1024, 0, stream>>>(sel, offs, rowmap, invmap, rbGroup, rbRow0);

    // 3: fused gate+up (flattened grid, XCD swizzle)
    gemm_gu<<<dim3(8 * MAXRB), 256, 0, stream>>>(
        x_bf, WtG, WtU, SWtG, SWtU, Hbuf, offs, rowmap, rbGroup, rbRow0);

    // 4: down projection (flattened grid, XCD swizzle)
    gemm_down<<<dim3(8 * MAXRB), 256, 0, stream>>>(
        Hbuf, WtD, SWtD, EO, offs, rbGroup, rbRow0);

    // 5: combine
    combine_k<<<dim3(T_TOK), 256, 0, stream>>>(out, EO, invmap, wts);
}